// Round 5
// baseline (223.576 us; speedup 1.0000x reference)
//
#include <hip/hip_runtime.h>
#include <hip/hip_cooperative_groups.h>
#include <math.h>

// JacobiMachine: 1000 steps of masked 5-point Jacobi averaging on 512x512.
// x0 = exp(-50((X-.5)^2+(Y-.5)^2)) with X,Y RANDOM fields -> white spectrum.
// Step 1 explicit (handles x0's nonzero boundary); steps 2..1000 via exact
// eigendecomposition of the interior Dirichlet operator:
//   phi_m[i] = sin(m*pi*i/511),  lam_mn = 0.5*(cos(m*pi/511)+cos(n*pi/511))
// Surviving spectrum after ^999: m in {1..64} (lam~+1) and {447..510}
// (lam~-1 checkerboard). 128 modes/dim; largest discarded |lam|^999 ~ 3e-18.
//
// Round 5: single cooperative kernel, 256 blocks x 256 threads (1 block/CU),
// 5 phases separated by grid.sync(). Kills 3 graph-node overheads and the
// R4 suspect (k_m23 at 1 wave/CU with uncoalesced per-lane-row S reads).
// Every phase now has >=512 waves of parallelism and coalesced loads.

#define HW 512
#define NP 128

namespace cg = cooperative_groups;

__device__ __forceinline__ int mode_of(int p) {   // p=0..127 -> {1..64} u {447..510}
    return (p < 64) ? (p + 1) : (p + 383);
}

__device__ __forceinline__ float gauss(const float* __restrict__ X,
                                       const float* __restrict__ Y, int idx) {
    float dx = X[idx] - 0.5f, dy = Y[idx] - 0.5f;
    return expf(-50.0f * (dx * dx + dy * dy));
}

__global__ void __launch_bounds__(256)
k_fused(const float* __restrict__ X, const float* __restrict__ Y,
        float* __restrict__ x1, float* __restrict__ S,
        float* __restrict__ C1, float* __restrict__ D,
        float* __restrict__ E, float* __restrict__ out) {
    cg::grid_group grid = cg::this_grid();
    __shared__ float lds[1024];                 // reused across phases
    const int b = blockIdx.x, t = threadIdx.x;  // 256 blocks, 256 threads

    // ---- P0: x1 = masked stencil of gaussian field;  S basis (fp64 sin) ----
    // x1: 4 elems/thread. Neighbors recomputed from X,Y == materializing x0.
    #pragma unroll
    for (int k = 0; k < 4; k++) {
        int idx = b * 1024 + k * 256 + t;
        int i = idx >> 9, j = idx & 511;
        float v = 0.0f;
        if (i > 0 && i < HW - 1 && j > 0 && j < HW - 1) {
            v = 0.25f * (gauss(X, Y, idx - HW) + gauss(X, Y, idx + HW) +
                         gauss(X, Y, idx - 1)  + gauss(X, Y, idx + 1));
        }
        x1[idx] = v;
    }
    {   // S[p][i] = sin(m_p*i*pi/511); S[p][0]=S[p][511]=0 exactly.
        int idx = b * 256 + t;                  // 65536 total
        int p = idx >> 9, i = idx & 511;
        long m = (long)mode_of(p);
        long tt = (m * (long)i) % 1022;         // exact arg reduction (period 1022)
        S[idx] = (float)sin((double)tt * (M_PI / 511.0));
    }
    grid.sync();

    // ---- P1: C1[p][j] = sum_i S[p,i]*x1[i,j] ---- (1 output/thread)
    {
        int p = b >> 1, j = (b & 1) * 256 + t;
        const float* Sp = S + p * HW;           // wave-uniform -> scalar loads
        float acc = 0.f;
        #pragma unroll 8
        for (int i = 0; i < HW; i++) acc += Sp[i] * x1[i * HW + j];  // coalesced
        C1[p * HW + j] = acc;
    }
    grid.sync();

    // ---- P2: D[p][q] = lam_pq^999*(2/511)^2 * sum_i C1[p,i]*S[q,i] ----
    // block: p = b>>1, 64 q's; thread: (q, i-quarter); LDS reduce of quarters.
    {
        int p = b >> 1, q0 = (b & 1) * 64;
        float* c1row = lds;                     // [512]
        float* red   = lds + 512;               // [256]
        ((float4*)c1row)[t & 127] = ((const float4*)(C1 + p * HW))[t & 127];
        __syncthreads();
        int qi = t & 63, quarter = t >> 6;
        const float* Sq = S + (q0 + qi) * HW + quarter * 128;
        const float* cq = c1row + quarter * 128;
        float acc = 0.f;
        #pragma unroll 8
        for (int i = 0; i < 128; i++) acc += cq[i] * Sq[i];
        red[quarter * 64 + qi] = acc;
        __syncthreads();
        if (t < 64) {
            int q = q0 + t;
            float s = red[t] + red[64 + t] + red[128 + t] + red[192 + t];
            double lp = cos((double)mode_of(p) * M_PI / 511.0);
            double lq = cos((double)mode_of(q) * M_PI / 511.0);
            double lam = 0.5 * (lp + lq);
            double mag = pow(fabs(lam), 999.0);
            if (lam < 0.0) mag = -mag;          // 999 odd
            D[p * NP + q] = (float)((double)s * mag * (2.0 / 511.0) * (2.0 / 511.0));
        }
        __syncthreads();                        // lds reused next phase
    }
    grid.sync();

    // ---- P3: E[p][j] = sum_q D[p,q]*S[q,j] ---- (1 output/thread)
    {
        int p = b >> 1, j = (b & 1) * 256 + t;
        float* drow = lds;                      // [128]
        if (t < 128) drow[t] = D[p * NP + t];
        __syncthreads();
        float acc = 0.f;
        #pragma unroll 8
        for (int q = 0; q < NP; q++) acc += drow[q] * S[q * HW + j];  // coalesced
        E[p * HW + j] = acc;
    }
    grid.sync();

    // ---- P4: out[i][j] = sum_p S[p,i]*E[p,j] ---- (4 outputs/thread)
    // Boundary rows/cols exact 0 via S[p][0]=S[p][511]=0.
    {
        int i0 = b * 2;
        float a00 = 0.f, a01 = 0.f, a10 = 0.f, a11 = 0.f;
        #pragma unroll 4
        for (int p = 0; p < NP; p++) {
            float e1 = E[p * HW + t];           // coalesced
            float e2 = E[p * HW + t + 256];     // coalesced
            float s1 = S[p * HW + i0];          // wave-uniform -> scalar
            float s2 = S[p * HW + i0 + 1];
            a00 += s1 * e1; a01 += s1 * e2;
            a10 += s2 * e1; a11 += s2 * e2;
        }
        out[(i0 + 0) * HW + t]       = a00;
        out[(i0 + 0) * HW + t + 256] = a01;
        out[(i0 + 1) * HW + t]       = a10;
        out[(i0 + 1) * HW + t + 256] = a11;
    }
}

// ---------------- launcher ----------------

extern "C" void kernel_launch(void* const* d_in, const int* in_sizes, int n_in,
                              void* d_out, int out_size, void* d_ws, size_t ws_size,
                              hipStream_t stream) {
    const float* X = (const float*)d_in[0];
    const float* Y = (const float*)d_in[1];
    float* out = (float*)d_out;

    float* ws = (float*)d_ws;
    float* x1 = ws;                       // 512*512
    float* S  = x1 + HW * HW;             // 128*512
    float* C1 = S + NP * HW;              // 128*512
    float* D  = C1 + NP * HW;             // 128*128
    float* E  = D + NP * NP;              // 128*512

    void* args[] = { (void*)&X, (void*)&Y, (void*)&x1, (void*)&S,
                     (void*)&C1, (void*)&D, (void*)&E, (void*)&out };
    hipLaunchCooperativeKernel((const void*)k_fused, dim3(256), dim3(256),
                               args, 0, stream);
}

// Round 6
// 87.529 us; speedup vs baseline: 2.5543x; 2.5543x over previous
//
#include <hip/hip_runtime.h>
#include <math.h>

// JacobiMachine: 1000 steps of masked 5-point Jacobi averaging on 512x512.
// Spectral method (exact): step 1 explicit, steps 2..1000 via eigen-basis
//   phi_m[i]=sin(m*pi*i/511), lam_mn=0.5*(cos(m*pi/511)+cos(n*pi/511)),
// keeping the two surviving corners m in {1..64} u {447..510} (128 modes/dim,
// largest discarded |lam|^999 ~ 3e-18).
//
// Round 6: cooperative fusion REVERTED (grid.sync ~35us each on 8-XCD chip).
// 5 graph nodes, each with >=1024-block parallelism, coalesced loads, and
// HW fp32 atomics (unsafeAtomicAdd) for split-K partial sums.

#define HW 512
#define NP 128

__device__ __forceinline__ int mode_of(int p) {   // p=0..127 -> {1..64} u {447..510}
    return (p < 64) ? (p + 1) : (p + 383);
}

__device__ __forceinline__ float gauss(const float* __restrict__ X,
                                       const float* __restrict__ Y, int idx) {
    float dx = X[idx] - 0.5f, dy = Y[idx] - 0.5f;
    return expf(-50.0f * (dx * dx + dy * dy));
}

// Block ranges:
//  [0,1024)    x1[idx] = masked 5-pt avg of gaussian (== one reference step)
//  [1024,1280) S[p][i]  = sin(m_p*i*pi/511)      (p-major, for m1/m3/m4)
//  [1280,1536) ST[i][p] = sin(m_p*i*pi/511)      (i-major, coalesced in m2)
//  [1536,1600) L[p][q]  = lam_pq^999*(2/511)^2   (fp64 pow, sign kept, once)
//  [1600,1664) C1 = 0   (atomic target)
//  [1664,1680) D  = 0   (atomic target)
__global__ void k_prep(const float* __restrict__ X, const float* __restrict__ Y,
                       float* __restrict__ x1, float* __restrict__ S,
                       float* __restrict__ ST, float* __restrict__ L,
                       float* __restrict__ C1, float* __restrict__ D) {
    int b = blockIdx.x, t = threadIdx.x;
    if (b < 1024) {
        int idx = b * 256 + t;
        int i = idx >> 9, j = idx & 511;
        float v = 0.0f;
        if (i > 0 && i < HW - 1 && j > 0 && j < HW - 1) {
            v = 0.25f * (gauss(X, Y, idx - HW) + gauss(X, Y, idx + HW) +
                         gauss(X, Y, idx - 1)  + gauss(X, Y, idx + 1));
        }
        x1[idx] = v;
    } else if (b < 1280) {
        int idx = (b - 1024) * 256 + t;
        int p = idx >> 9, i = idx & 511;
        long tt = ((long)mode_of(p) * (long)i) % 1022;   // exact reduction
        S[idx] = (float)sin((double)tt * (M_PI / 511.0));
    } else if (b < 1536) {
        int idx = (b - 1280) * 256 + t;
        int i = idx >> 7, p = idx & 127;
        long tt = ((long)mode_of(p) * (long)i) % 1022;
        ST[idx] = (float)sin((double)tt * (M_PI / 511.0));
    } else if (b < 1600) {
        int idx = (b - 1536) * 256 + t;                  // 16384 total
        int p = idx >> 7, q = idx & 127;
        double lp = cos((double)mode_of(p) * M_PI / 511.0);
        double lq = cos((double)mode_of(q) * M_PI / 511.0);
        double lam = 0.5 * (lp + lq);
        double mag = pow(fabs(lam), 999.0);
        if (lam < 0.0) mag = -mag;                       // 999 odd
        L[idx] = (float)(mag * (2.0 / 511.0) * (2.0 / 511.0));
    } else if (b < 1664) {
        ((float4*)C1)[(b - 1600) * 256 + t] = float4{0.f, 0.f, 0.f, 0.f};
    } else {
        ((float4*)D)[(b - 1664) * 256 + t] = float4{0.f, 0.f, 0.f, 0.f};
    }
}

// C1[p][j] += sum_{i in chunk} S[p,i]*x1[i,j]
// grid (jc=2, p=128, ic=4) x 256 = 1024 blocks; 128-iter loop; S scalar, x1 coalesced.
__global__ void k_m1(const float* __restrict__ S, const float* __restrict__ x1,
                     float* __restrict__ C1) {
    int j = blockIdx.x * 256 + threadIdx.x;
    int p = blockIdx.y;
    int i0 = blockIdx.z * 128;
    const float* Sp = S + p * HW + i0;
    const float* xp = x1 + i0 * HW + j;
    float acc = 0.f;
    #pragma unroll 8
    for (int i = 0; i < 128; i++) acc += Sp[i] * xp[i * HW];
    unsafeAtomicAdd(&C1[p * HW + j], acc);
}

// D[p][q] += L[p][q] * sum_{j in chunk} C1[p,j]*ST[j,q]
// grid (p=128, jc=8) x 128 threads = 1024 blocks; ST fully coalesced.
__global__ void k_m2(const float* __restrict__ C1, const float* __restrict__ ST,
                     const float* __restrict__ L, float* __restrict__ D) {
    __shared__ float c1[64];
    int p = blockIdx.x, jc = blockIdx.y, q = threadIdx.x;
    if (q < 64) c1[q] = C1[p * HW + jc * 64 + q];
    __syncthreads();
    const float* STp = ST + jc * 64 * NP + q;
    float acc = 0.f;
    #pragma unroll 8
    for (int j = 0; j < 64; j++) acc += c1[j] * STp[j * NP];
    unsafeAtomicAdd(&D[p * NP + q], acc * L[p * NP + q]);
}

// E[p][j] = sum_q D[p,q]*S[q,j]; grid (jc=2, p=128) x 256; D-row in LDS, S coalesced.
__global__ void k_m3(const float* __restrict__ D, const float* __restrict__ S,
                     float* __restrict__ E) {
    __shared__ float drow[NP];
    int j = blockIdx.x * 256 + threadIdx.x;
    int p = blockIdx.y;
    if (threadIdx.x < NP) drow[threadIdx.x] = D[p * NP + threadIdx.x];
    __syncthreads();
    float acc = 0.f;
    #pragma unroll 8
    for (int q = 0; q < NP; q++) acc += drow[q] * S[q * HW + j];
    E[p * HW + j] = acc;
}

// out[i][j] = sum_p S[p,i]*E[p,j]; grid (jc=2, i=512) x 256 = 1024 blocks.
// Boundary rows/cols exact 0 because S[p][0]=S[p][511]=0.
__global__ void k_m4(const float* __restrict__ S, const float* __restrict__ E,
                     float* __restrict__ out) {
    int j = blockIdx.x * 256 + threadIdx.x;
    int i = blockIdx.y;
    float acc = 0.f;
    #pragma unroll 8
    for (int p = 0; p < NP; p++) acc += S[p * HW + i] * E[p * HW + j];
    out[i * HW + j] = acc;
}

// ---------------- launcher ----------------

extern "C" void kernel_launch(void* const* d_in, const int* in_sizes, int n_in,
                              void* d_out, int out_size, void* d_ws, size_t ws_size,
                              hipStream_t stream) {
    const float* X = (const float*)d_in[0];
    const float* Y = (const float*)d_in[1];
    float* out = (float*)d_out;

    float* ws = (float*)d_ws;
    float* x1 = ws;                       // 512*512
    float* S  = x1 + HW * HW;             // 128*512
    float* ST = S + NP * HW;              // 512*128
    float* L  = ST + HW * NP;             // 128*128
    float* C1 = L + NP * NP;              // 128*512
    float* D  = C1 + NP * HW;             // 128*128
    float* E  = D + NP * NP;              // 128*512

    k_prep<<<dim3(1680),        dim3(256), 0, stream>>>(X, Y, x1, S, ST, L, C1, D);
    k_m1  <<<dim3(2, NP, 4),    dim3(256), 0, stream>>>(S, x1, C1);
    k_m2  <<<dim3(NP, 8),       dim3(128), 0, stream>>>(C1, ST, L, D);
    k_m3  <<<dim3(2, NP),       dim3(256), 0, stream>>>(D, S, E);
    k_m4  <<<dim3(2, HW),       dim3(256), 0, stream>>>(S, E, out);
}

// Round 7
// 87.154 us; speedup vs baseline: 2.5653x; 1.0043x over previous
//
#include <hip/hip_runtime.h>
#include <math.h>

// JacobiMachine: 1000 steps of masked 5-point Jacobi averaging on 512x512.
// Spectral method (exact): step 1 explicit, steps 2..1000 via eigen-basis
//   phi_m[i]=sin(m*pi*i/511), lam_mn=0.5*(cos(m*pi/511)+cos(n*pi/511)),
// keeping the two surviving corners m in {1..64} u {447..510} (128 modes/dim,
// largest discarded |lam|^999 ~ 3e-18).
//
// Round 7: halve m1/m4 L2 traffic (2 rows per block, 512 blocks, 8 waves/CU).
// Harness floor measured ~70us (R5: 223.6 total - 153.8 kernel); controllable
// share is ~19us of kernels+nodes. Cooperative fusion stays reverted
// (grid.sync ~35us each on 8 XCDs).

#define HW 512
#define NP 128

__device__ __forceinline__ int mode_of(int p) {   // p=0..127 -> {1..64} u {447..510}
    return (p < 64) ? (p + 1) : (p + 383);
}

__device__ __forceinline__ float gauss(const float* __restrict__ X,
                                       const float* __restrict__ Y, int idx) {
    float dx = X[idx] - 0.5f, dy = Y[idx] - 0.5f;
    return expf(-50.0f * (dx * dx + dy * dy));
}

// Block ranges:
//  [0,1024)    x1[idx] = masked 5-pt avg of gaussian (== one reference step)
//  [1024,1280) S[p][i]  = sin(m_p*i*pi/511)      (p-major, for m1/m3/m4)
//  [1280,1536) ST[i][p] = sin(m_p*i*pi/511)      (i-major, coalesced in m2)
//  [1536,1600) L[p][q]  = lam_pq^999*(2/511)^2   (fp64 pow, sign kept, once)
//  [1600,1664) C1 = 0   (atomic target)
//  [1664,1680) D  = 0   (atomic target)
__global__ void k_prep(const float* __restrict__ X, const float* __restrict__ Y,
                       float* __restrict__ x1, float* __restrict__ S,
                       float* __restrict__ ST, float* __restrict__ L,
                       float* __restrict__ C1, float* __restrict__ D) {
    int b = blockIdx.x, t = threadIdx.x;
    if (b < 1024) {
        int idx = b * 256 + t;
        int i = idx >> 9, j = idx & 511;
        float v = 0.0f;
        if (i > 0 && i < HW - 1 && j > 0 && j < HW - 1) {
            v = 0.25f * (gauss(X, Y, idx - HW) + gauss(X, Y, idx + HW) +
                         gauss(X, Y, idx - 1)  + gauss(X, Y, idx + 1));
        }
        x1[idx] = v;
    } else if (b < 1280) {
        int idx = (b - 1024) * 256 + t;
        int p = idx >> 9, i = idx & 511;
        long tt = ((long)mode_of(p) * (long)i) % 1022;   // exact reduction
        S[idx] = (float)sin((double)tt * (M_PI / 511.0));
    } else if (b < 1536) {
        int idx = (b - 1280) * 256 + t;
        int i = idx >> 7, p = idx & 127;
        long tt = ((long)mode_of(p) * (long)i) % 1022;
        ST[idx] = (float)sin((double)tt * (M_PI / 511.0));
    } else if (b < 1600) {
        int idx = (b - 1536) * 256 + t;                  // 16384 total
        int p = idx >> 7, q = idx & 127;
        double lp = cos((double)mode_of(p) * M_PI / 511.0);
        double lq = cos((double)mode_of(q) * M_PI / 511.0);
        double lam = 0.5 * (lp + lq);
        double mag = pow(fabs(lam), 999.0);
        if (lam < 0.0) mag = -mag;                       // 999 odd
        L[idx] = (float)(mag * (2.0 / 511.0) * (2.0 / 511.0));
    } else if (b < 1664) {
        ((float4*)C1)[(b - 1600) * 256 + t] = float4{0.f, 0.f, 0.f, 0.f};
    } else {
        ((float4*)D)[(b - 1664) * 256 + t] = float4{0.f, 0.f, 0.f, 0.f};
    }
}

// C1[p][j] += sum_{i in chunk} S[p,i]*x1[i,j]
// grid (jc=2, pg=64, ic=4) x 256 = 512 blocks (8 waves/CU), 2 p-rows/block:
// halves x1 re-reads vs 1-p blocks (128MB -> 64MB L2) with 2-chain ILP.
__global__ void k_m1(const float* __restrict__ S, const float* __restrict__ x1,
                     float* __restrict__ C1) {
    int j = blockIdx.x * 256 + threadIdx.x;
    int p0 = blockIdx.y * 2;
    int i0 = blockIdx.z * 128;
    const float* S0 = S + p0 * HW + i0;        // wave-uniform -> scalar loads
    const float* S1 = S0 + HW;
    const float* xp = x1 + i0 * HW + j;        // coalesced, L2-resident
    float a0 = 0.f, a1 = 0.f;
    #pragma unroll 8
    for (int i = 0; i < 128; i++) {
        float x = xp[i * HW];
        a0 += S0[i] * x;
        a1 += S1[i] * x;
    }
    unsafeAtomicAdd(&C1[p0 * HW + j], a0);
    unsafeAtomicAdd(&C1[(p0 + 1) * HW + j], a1);
}

// D[p][q] += L[p][q] * sum_{j in chunk} C1[p,j]*ST[j,q]
// grid (p=128, jc=8) x 128 threads = 1024 blocks; ST fully coalesced.
__global__ void k_m2(const float* __restrict__ C1, const float* __restrict__ ST,
                     const float* __restrict__ L, float* __restrict__ D) {
    __shared__ float c1[64];
    int p = blockIdx.x, jc = blockIdx.y, q = threadIdx.x;
    if (q < 64) c1[q] = C1[p * HW + jc * 64 + q];
    __syncthreads();
    const float* STp = ST + jc * 64 * NP + q;
    float acc = 0.f;
    #pragma unroll 8
    for (int j = 0; j < 64; j++) acc += c1[j] * STp[j * NP];
    unsafeAtomicAdd(&D[p * NP + q], acc * L[p * NP + q]);
}

// E[p][j] = sum_q D[p,q]*S[q,j]; grid (jc=2, p=128) x 256; D-row in LDS, S coalesced.
__global__ void k_m3(const float* __restrict__ D, const float* __restrict__ S,
                     float* __restrict__ E) {
    __shared__ float drow[NP];
    int j = blockIdx.x * 256 + threadIdx.x;
    int p = blockIdx.y;
    if (threadIdx.x < NP) drow[threadIdx.x] = D[p * NP + threadIdx.x];
    __syncthreads();
    float acc = 0.f;
    #pragma unroll 8
    for (int q = 0; q < NP; q++) acc += drow[q] * S[q * HW + j];
    E[p * HW + j] = acc;
}

// out[i][j] = sum_p S[p,i]*E[p,j]
// grid (jc=2, ig=256) x 256 = 512 blocks (8 waves/CU), 2 i-rows/block:
// halves E re-reads (128MB -> 64MB L2). Boundary exact 0 via S[p][0]=S[p][511]=0.
__global__ void k_m4(const float* __restrict__ S, const float* __restrict__ E,
                     float* __restrict__ out) {
    int j = blockIdx.x * 256 + threadIdx.x;
    int i0 = blockIdx.y * 2;
    float a0 = 0.f, a1 = 0.f;
    #pragma unroll 8
    for (int p = 0; p < NP; p++) {
        float e = E[p * HW + j];               // coalesced
        a0 += S[p * HW + i0] * e;              // wave-uniform -> scalar
        a1 += S[p * HW + i0 + 1] * e;
    }
    out[(i0 + 0) * HW + j] = a0;
    out[(i0 + 1) * HW + j] = a1;
}

// ---------------- launcher ----------------

extern "C" void kernel_launch(void* const* d_in, const int* in_sizes, int n_in,
                              void* d_out, int out_size, void* d_ws, size_t ws_size,
                              hipStream_t stream) {
    const float* X = (const float*)d_in[0];
    const float* Y = (const float*)d_in[1];
    float* out = (float*)d_out;

    float* ws = (float*)d_ws;
    float* x1 = ws;                       // 512*512
    float* S  = x1 + HW * HW;             // 128*512
    float* ST = S + NP * HW;              // 512*128
    float* L  = ST + HW * NP;             // 128*128
    float* C1 = L + NP * NP;              // 128*512
    float* D  = C1 + NP * HW;             // 128*128
    float* E  = D + NP * NP;              // 128*512

    k_prep<<<dim3(1680),        dim3(256), 0, stream>>>(X, Y, x1, S, ST, L, C1, D);
    k_m1  <<<dim3(2, 64, 4),    dim3(256), 0, stream>>>(S, x1, C1);
    k_m2  <<<dim3(NP, 8),       dim3(128), 0, stream>>>(C1, ST, L, D);
    k_m3  <<<dim3(2, NP),       dim3(256), 0, stream>>>(D, S, E);
    k_m4  <<<dim3(2, 256),      dim3(256), 0, stream>>>(S, E, out);
}